// Round 9
// baseline (461.088 us; speedup 1.0000x reference)
//
#include <hip/hip_runtime.h>
#include <hip/hip_bf16.h>
#include <math.h>

#define DI __device__ __forceinline__

constexpr int NN   = 20000;
constexpr int NE   = 160000;
constexpr int FIN  = 64;
constexpr int HIDC = 256;
constexpr int NH   = 4;
constexpr int NOUT = 3328;   // 3*1024 (QKV) + 256 (skip)
constexpr int CAPD = 128;    // per-node edge index stash capacity

typedef __attribute__((ext_vector_type(8))) short short8;
typedef __attribute__((ext_vector_type(4))) float f32x4;

DI float bf2f(unsigned short u) { return __uint_as_float(((unsigned)u) << 16); }

DI void gld16(const void* g, void* l) {
  __builtin_amdgcn_global_load_lds((const __attribute__((address_space(1))) unsigned*)g,
                                   (__attribute__((address_space(3))) unsigned*)l, 16, 0, 0);
}

// ---------------- merged input cast + degree count ----------------
__global__ void k_prep(const float* __restrict__ x, __hip_bfloat16* __restrict__ xb,
                       const int* __restrict__ dst, int* __restrict__ deg) {
  int gid = blockIdx.x * 256 + threadIdx.x;
  if (gid < NN * FIN) xb[gid] = __float2bfloat16(x[gid]);
  if (gid < NE) atomicAdd(&deg[dst[gid]], 1);
}

__global__ void k_scan(const int* __restrict__ deg, int* __restrict__ offs,
                       int* __restrict__ cursor, int n_) {
  __shared__ int part[1024];
  int tid = threadIdx.x;
  const int CH = (n_ + 1023) >> 10;
  int base = tid * CH;
  int s = 0;
  for (int i = 0; i < CH; ++i) { int idx = base + i; if (idx < n_) s += deg[idx]; }
  part[tid] = s;
  __syncthreads();
  for (int off = 1; off < 1024; off <<= 1) {
    int v = (tid >= off) ? part[tid - off] : 0;
    __syncthreads();
    part[tid] += v;
    __syncthreads();
  }
  int run = (tid == 0) ? 0 : part[tid - 1];
  for (int i = 0; i < CH; ++i) {
    int idx = base + i;
    if (idx < n_) { offs[idx] = run; cursor[idx] = run; run += deg[idx]; }
  }
  if (tid == 1023) offs[n_] = run;
}

__global__ void k_scatter(const int* __restrict__ dst, int* __restrict__ cursor,
                          int* __restrict__ eid, int e_) {
  int e = blockIdx.x * blockDim.x + threadIdx.x;
  if (e < e_) {
    int p = atomicAdd(&cursor[dst[e]], 1);
    eid[p] = e;
  }
}

// ---------------- deterministic segment order: insertion-sort each node's edges ------
__global__ void k_sort(const int* __restrict__ offs, int* __restrict__ eid, int n_) {
  int n = blockIdx.x * 256 + threadIdx.x;
  if (n >= n_) return;
  int s0 = offs[n], s1 = offs[n + 1];
  for (int i = s0 + 1; i < s1; ++i) {
    int v = eid[i];
    int j = i - 1;
    while (j >= s0 && eid[j] > v) { eid[j + 1] = eid[j]; --j; }
    eid[j + 1] = v;
  }
}

// ---------------- weight pack: Wt[n][k] = concat(wq|wk|wv|ws)[k][n], bf16 ----------------
template <int K>
__global__ void k_pack(const float* __restrict__ wq, const float* __restrict__ bq,
                       const float* __restrict__ wk, const float* __restrict__ bk,
                       const float* __restrict__ wv, const float* __restrict__ bv,
                       const float* __restrict__ ws, const float* __restrict__ bs,
                       __hip_bfloat16* __restrict__ Wt, float* __restrict__ biasp) {
  int n = blockIdx.x * 128 + threadIdx.x;  // 0..3327
  int k = blockIdx.y;                      // 0..K-1
  const float* w; const float* b; int off; int M;
  if (n < 1024)      { w = wq; b = bq; off = n;        M = 1024; }
  else if (n < 2048) { w = wk; b = bk; off = n - 1024; M = 1024; }
  else if (n < 3072) { w = wv; b = bv; off = n - 2048; M = 1024; }
  else               { w = ws; b = bs; off = n - 3072; M = 256;  }
  Wt[(size_t)n * K + k] = __float2bfloat16(w[(size_t)k * M + off]);
  if (k == 0) biasp[n] = b[off];
}

// ---------------- per-wave barrier-free MFMA GEMM -> q/k/v bf16 | skip f32 ----------------
template <int K>
__global__ __launch_bounds__(64, 2) void k_gemm_pw(
    const __hip_bfloat16* __restrict__ X, const __hip_bfloat16* __restrict__ Wt,
    const float* __restrict__ biasp,
    __hip_bfloat16* __restrict__ qb, __hip_bfloat16* __restrict__ kb,
    __hip_bfloat16* __restrict__ vb, float* __restrict__ skipf,
    int nrows, int NCB, int NCH, int TPC, int RT) {
  __shared__ char lds[16384 + 2304];  // 2 x 8KB A dbuf + 16x144B epilogue scratch
  const int l = threadIdx.x;          // 0..63

  // XCD grouping: blocks on one XCD share a row-chunk's A panel.
  const int nwg = NCB * NCH;          // 2080, divisible by 8
  const int per = nwg >> 3;
  const int w = (blockIdx.x & 7) * per + (blockIdx.x >> 3);
  const int chunk = w / NCB;
  const int ct = w % NCB;
  const int bn = ct * 64;
  const int t0 = chunk * TPC;
  int t1 = t0 + TPC; if (t1 > RT) t1 = RT;
  constexpr int KT = K / 64;          // BK=64 chunks per tile
  constexpr int NS = K / 32;          // k-steps of 32 (b-frag count per n)

  const int lm = l & 15, lk = l >> 4;

  // ---- B panel -> registers (once per block) ----
  short8 bfr[4 * NS];
  {
    const __hip_bfloat16* bp = Wt + (size_t)(bn + lm) * K + lk * 8;
#pragma unroll
    for (int n = 0; n < 4; ++n)
#pragma unroll
      for (int s = 0; s < NS; ++s)
        bfr[n * NS + s] = *(const short8*)(bp + (size_t)n * 16 * K + s * 32);
  }
  float bia[4];
#pragma unroll
  for (int n = 0; n < 4; ++n) bia[n] = biasp[bn + n * 16 + lm];

  // output routing (uniform per block)
  __hip_bfloat16* dst16 = nullptr; int cb16 = 0;
  if (bn < 1024)      { dst16 = qb; cb16 = bn; }
  else if (bn < 2048) { dst16 = kb; cb16 = bn - 1024; }
  else if (bn < 3072) { dst16 = vb; cb16 = bn - 2048; }

  // ---- A staging (swizzled source, linear LDS dest) ----
  const int jrow = l >> 3;                     // 0..7 (row within 8-row group)
  const int cslot = (l & 7) ^ jrow;            // inverse-swizzled 16B chunk
  auto STAGE = [&](int buf, int t, int kt) {
    char* db = lds + buf * 8192;
#pragma unroll
    for (int j = 0; j < 8; ++j) {
      int r = t * 64 + j * 8 + jrow;
      if (r >= nrows) r = nrows - 1;
      gld16(X + (size_t)r * K + kt * 64 + cslot * 8, db + j * 1024 + l * 16);
    }
  };

  int buf = 0;
  STAGE(0, t0, 0);
  for (int t = t0; t < t1; ++t) {
    f32x4 acc[4][4] = {};
#pragma unroll
    for (int kt = 0; kt < KT; ++kt) {
      int nt = t, nk = kt + 1;
      if (nk == KT) { nt = (t + 1 < t1) ? t + 1 : t; nk = 0; }
      STAGE(buf ^ 1, nt, nk);
      asm volatile("s_waitcnt vmcnt(8)" ::: "memory");  // current chunk resident
      const char* db = lds + buf * 8192;
#pragma unroll
      for (int s2 = 0; s2 < 2; ++s2) {
        short8 a[4];
#pragma unroll
        for (int m = 0; m < 4; ++m) {
          int row = m * 16 + lm;
          a[m] = *(const short8*)(db + row * 128 + (((s2 * 4 + lk) ^ (lm & 7)) * 16));
        }
#pragma unroll
        for (int m = 0; m < 4; ++m)
#pragma unroll
          for (int n = 0; n < 4; ++n)
            acc[m][n] = __builtin_amdgcn_mfma_f32_16x16x32_bf16(
                a[m], bfr[n * NS + kt * 2 + s2], acc[m][n], 0, 0, 0);
      }
      buf ^= 1;
    }

    const int tbase = t * 64;
    if (dst16 != nullptr) {
      // ---- epilogue: 16 rows at a time through wave-private scratch, bf16 stores ----
      char* sc = lds + 16384;
      const int srow = l >> 2, qc = l & 3;
#pragma unroll
      for (int m = 0; m < 4; ++m) {
#pragma unroll
        for (int n = 0; n < 4; ++n)
#pragma unroll
          for (int r = 0; r < 4; ++r)
            *(__hip_bfloat16*)(sc + (lk * 4 + r) * 144 + (n * 16 + lm) * 2) =
                __float2bfloat16(acc[m][n][r] + bia[n]);
        const char* sr = sc + srow * 144 + qc * 32;
        short8 ta = *(const short8*)(sr);
        short8 tb = *(const short8*)(sr + 16);
        int grow = tbase + m * 16 + srow;
        if (grow < nrows) {
          ushort* o = (ushort*)dst16 + (size_t)grow * 1024 + cb16 + qc * 16;
          *(short8*)o = ta;
          *(short8*)(o + 8) = tb;
        }
      }
    } else {
      // ---- skip block: direct f32 stores (no bf16 round-trip) ----
      const int cb = bn - 3072;
#pragma unroll
      for (int m = 0; m < 4; ++m)
#pragma unroll
        for (int n = 0; n < 4; ++n)
#pragma unroll
          for (int r = 0; r < 4; ++r) {
            int row = tbase + m * 16 + lk * 4 + r;
            if (row < nrows) skipf[(size_t)row * HIDC + cb + n * 16 + lm] = acc[m][n][r] + bia[n];
          }
    }
  }
  asm volatile("s_waitcnt vmcnt(0)" ::: "memory");  // drain dangling prefetch
}

// ---------------- fused attention: 16 lanes/edge x 4 edges in flight (all bf16) ----------
__global__ __launch_bounds__(256) void k_attn(
    const __hip_bfloat16* __restrict__ qb, const __hip_bfloat16* __restrict__ kb,
    const __hip_bfloat16* __restrict__ vb,
    const int* __restrict__ offs, const int* __restrict__ eid,
    const int* __restrict__ src, const float* __restrict__ skipf,
    __hip_bfloat16* __restrict__ outb, float* __restrict__ outf) {
  int n = blockIdx.x;
  int s0 = offs[n], s1 = offs[n + 1];
  int deg = s1 - s0;
  int tid = threadIdx.x;
  if (deg == 0) {  // out = skip
    if (tid < 64) {
      int c = tid * 4;
      float4 sv = *(const float4*)(skipf + (size_t)n * HIDC + c);
      if (outb != nullptr) {
        ushort* ob = (ushort*)outb + (size_t)n * HIDC + c;
        ob[0] = __bfloat16_as_ushort(__float2bfloat16(sv.x));
        ob[1] = __bfloat16_as_ushort(__float2bfloat16(sv.y));
        ob[2] = __bfloat16_as_ushort(__float2bfloat16(sv.z));
        ob[3] = __bfloat16_as_ushort(__float2bfloat16(sv.w));
      }
      if (outf != nullptr) *(float4*)(outf + (size_t)n * HIDC + c) = sv;
    }
    return;
  }
  __shared__ int ses[CAPD];
  __shared__ float red[NH][HIDC];
  int h = tid >> 6, lane = tid & 63;
  int g = lane >> 4, j = lane & 15;
  int dc = deg < CAPD ? deg : CAPD;
  for (int i = tid; i < dc; i += 256) ses[i] = src[eid[s0 + i]];
  __syncthreads();

  // Q fragment: 16 dims per lane (bf16 -> f32)
  float q[16];
  {
    const ushort* qr = (const ushort*)qb + (size_t)n * 1024 + h * 256 + j * 16;
    short8 q0 = *(const short8*)(qr);
    short8 q1 = *(const short8*)(qr + 8);
#pragma unroll
    for (int d = 0; d < 8; ++d) { q[d] = bf2f((unsigned short)q0[d]); q[8 + d] = bf2f((unsigned short)q1[d]); }
  }

  float acc[16];
#pragma unroll
  for (int d = 0; d < 16; ++d) acc[d] = 0.f;
  float denom = 0.f;

  for (int i0 = 0; i0 < deg; i0 += 4) {
    int e = i0 + g;
    bool valid = e < deg;
    int s;
    if (valid) s = (e < CAPD) ? ses[e] : src[eid[s0 + e]];
    else       s = ses[0];
    const ushort* kr = (const ushort*)kb + (size_t)s * 1024 + h * 256 + j * 16;
    short8 k0 = *(const short8*)(kr);
    short8 k1 = *(const short8*)(kr + 8);
    const ushort* vr = (const ushort*)vb + (size_t)s * 1024 + h * 256 + j * 16;
    short8 v0 = *(const short8*)(vr);
    short8 v1 = *(const short8*)(vr + 8);
    float p = 0.f;
#pragma unroll
    for (int d = 0; d < 8; ++d) {
      p = fmaf(q[d], bf2f((unsigned short)k0[d]), p);
      p = fmaf(q[8 + d], bf2f((unsigned short)k1[d]), p);
    }
    p += __shfl_xor(p, 1);
    p += __shfl_xor(p, 2);
    p += __shfl_xor(p, 4);
    p += __shfl_xor(p, 8);
    float wgt = valid ? __expf(p * 0.0625f) : 0.f;
    denom += wgt;
#pragma unroll
    for (int d = 0; d < 8; ++d) {
      acc[d] = fmaf(wgt, bf2f((unsigned short)v0[d]), acc[d]);
      acc[8 + d] = fmaf(wgt, bf2f((unsigned short)v1[d]), acc[8 + d]);
    }
  }

  // cross-group reduce (lane strides 16, 32)
#pragma unroll
  for (int d = 0; d < 16; ++d) {
    acc[d] += __shfl_xor(acc[d], 16);
    acc[d] += __shfl_xor(acc[d], 32);
  }
  denom += __shfl_xor(denom, 16);
  denom += __shfl_xor(denom, 32);
  float dinv = 1.f / (denom + 1e-16f);
  if (g == 0) {
#pragma unroll
    for (int d = 0; d < 16; ++d) red[h][j * 16 + d] = acc[d] * dinv;
  }
  __syncthreads();
  if (tid < 64) {
    int c0 = tid * 4;
    float4 sv = *(const float4*)(skipf + (size_t)n * HIDC + c0);
    float sk[4] = {sv.x, sv.y, sv.z, sv.w};
#pragma unroll
    for (int jj = 0; jj < 4; ++jj) {
      float m = (red[0][c0 + jj] + red[1][c0 + jj] + red[2][c0 + jj] + red[3][c0 + jj]) * 0.25f;
      float val = m + sk[jj];
      if (outb != nullptr) ((ushort*)outb)[(size_t)n * HIDC + c0 + jj] = __bfloat16_as_ushort(__float2bfloat16(val));
      if (outf != nullptr) outf[(size_t)n * HIDC + c0 + jj] = val;
    }
  }
}

// ---------------- batch norm stats: deterministic two-stage ----------------
__global__ void k_bnstats(const float* __restrict__ x, float* __restrict__ psum,
                          float* __restrict__ psumsq) {
  int t = threadIdx.x, b = blockIdx.x;
  float s = 0.f, s2 = 0.f;
  for (int r = b; r < NN; r += 256) {
    float vv = x[(size_t)r * HIDC + t];
    s += vv; s2 += vv * vv;
  }
  psum[b * HIDC + t] = s;
  psumsq[b * HIDC + t] = s2;
}

__global__ void k_bnred(const float* __restrict__ psum, const float* __restrict__ psumsq,
                        float* __restrict__ sums, float* __restrict__ sumsq) {
  int t = threadIdx.x;
  float s = 0.f, s2 = 0.f;
  for (int b = 0; b < 256; ++b) { s += psum[b * HIDC + t]; s2 += psumsq[b * HIDC + t]; }
  sums[t] = s;
  sumsq[t] = s2;
}

// ---------------- BN apply (stats inline) + linear head + softmax + rsu row ------
__global__ __launch_bounds__(256) void k_final(
    const float* __restrict__ x, const float* __restrict__ sums, const float* __restrict__ sumsq,
    const float* __restrict__ gamma, const float* __restrict__ beta,
    const float* __restrict__ lw, const float* __restrict__ lb,
    float* __restrict__ out, int n_) {
  int sub = threadIdx.x >> 6, lane = threadIdx.x & 63;
  int n = blockIdx.x * 4 + sub;
  if (n >= n_) return;
  int c = lane * 4;
  float4 sm  = *(const float4*)(sums + c);
  float4 sq  = *(const float4*)(sumsq + c);
  const float inv_n = 1.f / (float)n_;
  float mu0 = sm.x * inv_n, mu1 = sm.y * inv_n, mu2 = sm.z * inv_n, mu3 = sm.w * inv_n;
  float r0 = 1.f / sqrtf(fmaxf(sq.x * inv_n - mu0 * mu0, 0.f) + 1e-5f);
  float r1 = 1.f / sqrtf(fmaxf(sq.y * inv_n - mu1 * mu1, 0.f) + 1e-5f);
  float r2 = 1.f / sqrtf(fmaxf(sq.z * inv_n - mu2 * mu2, 0.f) + 1e-5f);
  float r3 = 1.f / sqrtf(fmaxf(sq.w * inv_n - mu3 * mu3, 0.f) + 1e-5f);
  const float* xr = x + (size_t)n * HIDC;
  float4 xv = *(const float4*)(xr + c);
  float4 gv = *(const float4*)(gamma + c);
  float4 bv = *(const float4*)(beta + c);
  float y0 = gv.x * (xv.x - mu0) * r0 + bv.x;
  float y1 = gv.y * (xv.y - mu1) * r1 + bv.y;
  float y2 = gv.z * (xv.z - mu2) * r2 + bv.z;
  float y3 = gv.w * (xv.w - mu3) * r3 + bv.w;
  float4 wa = *(const float4*)(lw + (size_t)c * 2);
  float4 wb = *(const float4*)(lw + (size_t)c * 2 + 4);
  float p0 = y0 * wa.x + y1 * wa.z + y2 * wb.x + y3 * wb.z;
  float p1 = y0 * wa.y + y1 * wa.w + y2 * wb.y + y3 * wb.w;
#pragma unroll
  for (int off = 32; off > 0; off >>= 1) {
    p0 += __shfl_xor(p0, off);
    p1 += __shfl_xor(p1, off);
  }
  if (n == 0) *(float4*)(out + (size_t)NN * 2 + c) = make_float4(y0, y1, y2, y3);
  if (lane == 0) {
    float l0 = fmaxf(p0 + lb[0], 0.f);
    float l1 = fmaxf(p1 + lb[1], 0.f);
    float m = fmaxf(l0, l1);
    float e0 = expf(l0 - m), e1 = expf(l1 - m);
    float inv = 1.f / (e0 + e1);
    out[(size_t)n * 2 + 0] = e0 * inv;
    out[(size_t)n * 2 + 1] = e1 * inv;
  }
}

// ---------------- launch ----------------
extern "C" void kernel_launch(void* const* d_in, const int* in_sizes, int n_in,
                              void* d_out, int out_size, void* d_ws, size_t ws_size,
                              hipStream_t stream) {
  const float* x0  = (const float*)d_in[0];
  const int*   ei  = (const int*)d_in[1];
  const float* wq1 = (const float*)d_in[2];  const float* bq1 = (const float*)d_in[3];
  const float* wk1 = (const float*)d_in[4];  const float* bk1 = (const float*)d_in[5];
  const float* wv1 = (const float*)d_in[6];  const float* bv1 = (const float*)d_in[7];
  const float* ws1 = (const float*)d_in[8];  const float* bs1 = (const float*)d_in[9];
  const float* wq2 = (const float*)d_in[10]; const float* bq2 = (const float*)d_in[11];
  const float* wk2 = (const float*)d_in[12]; const float* bk2 = (const float*)d_in[13];
  const float* wv2 = (const float*)d_in[14]; const float* bv2 = (const float*)d_in[15];
  const float* ws2 = (const float*)d_in[16]; const float* bs2 = (const float*)d_in[17];
  const float* gam = (const float*)d_in[18]; const float* bet = (const float*)d_in[19];
  const float* lw  = (const float*)d_in[20]; const float* lb  = (const float*)d_in[21];
  const int* srcv = ei;
  const int* dstv = ei + NE;

  char* p = (char*)d_ws;
  auto take = [&](size_t bytes) {
    char* r = p;
    p += (bytes + 255) & ~(size_t)255;
    return r;
  };
  __hip_bfloat16* qbuf = (__hip_bfloat16*)take((size_t)NN * 1024 * 2);
  __hip_bfloat16* kbuf = (__hip_bfloat16*)take((size_t)NN * 1024 * 2);
  __hip_bfloat16* vbuf = (__hip_bfloat16*)take((size_t)NN * 1024 * 2);
  float* skipf = (float*)take((size_t)NN * HIDC * 4);
  __hip_bfloat16* x0b = (__hip_bfloat16*)take((size_t)NN * FIN * 2);
  __hip_bfloat16* x2b = (__hip_bfloat16*)take((size_t)NN * HIDC * 2);
  __hip_bfloat16* Wt  = (__hip_bfloat16*)take((size_t)NOUT * HIDC * 2);
  float* x3    = (float*)take((size_t)NN * HIDC * 4);
  float* biasp = (float*)take((size_t)NOUT * 4);
  float* psum  = (float*)take(256 * HIDC * 4);
  float* psumsq= (float*)take(256 * HIDC * 4);
  float* bnbuf = (float*)take(2 * HIDC * 4);
  int* deg    = (int*)take((size_t)NN * 4);
  int* offs   = (int*)take((size_t)(NN + 1) * 4);
  int* cursor = (int*)take((size_t)NN * 4);
  int* eidb   = (int*)take((size_t)NE * 4);
  if ((size_t)(p - (char*)d_ws) > ws_size) return;

  float* sums  = bnbuf;
  float* sumsq = bnbuf + HIDC;

  hipMemsetAsync(deg, 0, (size_t)NN * 4, stream);
  k_prep<<<(NN * FIN + 255) / 256, 256, 0, stream>>>(x0, x0b, dstv, deg);
  k_scan<<<1, 1024, 0, stream>>>(deg, offs, cursor, NN);
  k_scatter<<<(NE + 255) / 256, 256, 0, stream>>>(dstv, cursor, eidb, NE);
  k_sort<<<(NN + 255) / 256, 256, 0, stream>>>(offs, eidb, NN);

  const int RT  = (NN + 63) / 64;   // 313 row tiles (64 rows each)
  const int NCB = NOUT / 64;        // 52 col tiles (64 cols each)
  const int NCH = 40;               // row chunks
  const int TPC = (RT + NCH - 1) / NCH;  // 8 tiles per chunk
  const int GRID = NCB * NCH;       // 2080 single-wave blocks
  // ---- layer 1 ----
  k_pack<FIN><<<dim3(NOUT / 128, FIN), 128, 0, stream>>>(wq1, bq1, wk1, bk1, wv1, bv1, ws1, bs1, Wt, biasp);
  k_gemm_pw<FIN><<<GRID, 64, 0, stream>>>(x0b, Wt, biasp, qbuf, kbuf, vbuf, skipf, NN, NCB, NCH, TPC, RT);
  k_attn<<<NN, 256, 0, stream>>>(qbuf, kbuf, vbuf, offs, eidb, srcv, skipf, x2b, nullptr);
  // ---- layer 2 ----
  k_pack<HIDC><<<dim3(NOUT / 128, HIDC), 128, 0, stream>>>(wq2, bq2, wk2, bk2, wv2, bv2, ws2, bs2, Wt, biasp);
  k_gemm_pw<HIDC><<<GRID, 64, 0, stream>>>(x2b, Wt, biasp, qbuf, kbuf, vbuf, skipf, NN, NCB, NCH, TPC, RT);
  k_attn<<<NN, 256, 0, stream>>>(qbuf, kbuf, vbuf, offs, eidb, srcv, skipf, nullptr, x3);
  // ---- BN + head ----
  k_bnstats<<<256, 256, 0, stream>>>(x3, psum, psumsq);
  k_bnred<<<1, 256, 0, stream>>>(psum, psumsq, sums, sumsq);
  k_final<<<(NN + 3) / 4, 256, 0, stream>>>(x3, sums, sumsq, gam, bet, lw, lb, (float*)d_out, NN);
}